// Round 2
// baseline (930.808 us; speedup 1.0000x reference)
//
#include <hip/hip_runtime.h>
#include <hip/hip_bf16.h>

// PatchGINEncoder on MI355X.
// NOTE (round-1 fix): harness converts ALL integer inputs to int32 on device.
// edge_index arrives as int32 [2*E]: ei[e]=src, ei[E+e]=dst. batch as int32 [N].
// Pipeline per launch:
//   prep (pack bf16 weights + fold BN) | x->bf16 | CSR build (count/scan/scatter)
//   3x { CSR gather z=h+Ah (A->B) -> GEMM1 in-place B -> GEMM2 in-place B -> swap }
//   sorted-batch mean pool -> fp32 proj + LayerNorm
// GEMM in-place is safe: each block stages its own 64 rows into LDS behind a
// __syncthreads() before writing exactly those rows; blocks own disjoint rows.
// Workspace use: ~59 MB.

#define GDEPTH 3

typedef __bf16 bf16x8 __attribute__((ext_vector_type(8)));
typedef float  f32x4  __attribute__((ext_vector_type(4)));
typedef __hip_bfloat16  bf16;
typedef __hip_bfloat162 bf162;

// ---------------- weight prep: pack W into B-fragment order, fold BN ----------------
// Bp[((kk*4+quad)*128 + n)*8 + j] = W[kk*32+quad*8+j][n]   (16B-contiguous frag loads)
__global__ void k_prep(const float* __restrict__ W1s, const float* __restrict__ W2s,
                       const float* __restrict__ b1s, const float* __restrict__ bng,
                       const float* __restrict__ bnb, const float* __restrict__ bnm,
                       const float* __restrict__ bnv,
                       bf16* __restrict__ Wp1, bf16* __restrict__ Wp2,
                       float* __restrict__ sArr, float* __restrict__ tArr) {
    int idx = blockIdx.x * 256 + threadIdx.x;      // [0, 6*16384)
    int l   = idx / 32768;
    int rem = idx - l * 32768;
    int w   = rem >> 14;
    int p   = rem & 16383;
    int j = p & 7, n = (p >> 3) & 127, tq = p >> 10;
    int quad = tq & 3, kk = tq >> 2;
    int k = kk * 32 + quad * 8 + j;
    const float* W = w ? W2s : W1s;
    bf16* Wp = w ? Wp2 : Wp1;
    Wp[l * 16384 + p] = __float2bfloat16(W[l * 16384 + k * 128 + n]);
    if (idx < GDEPTH * 128) {
        int ll = idx >> 7, c = idx & 127;
        float inv = rsqrtf(bnv[ll * 128 + c] + 1e-5f);
        float s = inv * bng[ll * 128 + c];
        sArr[idx] = s;
        tArr[idx] = (b1s[ll * 128 + c] - bnm[ll * 128 + c]) * s + bnb[ll * 128 + c];
    }
}

__global__ void k_convert_x(const float4* __restrict__ x, bf162* __restrict__ h, int n4) {
    int i = blockIdx.x * 256 + threadIdx.x;
    if (i >= n4) return;
    float4 v = x[i];
    bf162 a, b;
    a.x = __float2bfloat16(v.x); a.y = __float2bfloat16(v.y);
    b.x = __float2bfloat16(v.z); b.y = __float2bfloat16(v.w);
    h[2 * i] = a; h[2 * i + 1] = b;
}

// ---------------- CSR build (int32 indices) ----------------
__global__ void k_count(const int* __restrict__ ei, int* __restrict__ cnt, int E) {
    int e = blockIdx.x * 256 + threadIdx.x;
    if (e >= E) return;
    atomicAdd(&cnt[ei[E + e]], 1);             // dst row of edge_index
}

__global__ void k_count_batch(const int* __restrict__ batch, int* __restrict__ bcnt, int n) {
    int i = blockIdx.x * 256 + threadIdx.x;
    if (i >= n) return;
    atomicAdd(&bcnt[batch[i]], 1);
}

__global__ void k_scan_blocks(const int* __restrict__ cnt, int* __restrict__ rowp,
                              int* __restrict__ bsums, int n) {
    __shared__ int s[256];
    int t = threadIdx.x;
    int i = blockIdx.x * 256 + t;
    int v = (i < n) ? cnt[i] : 0;
    s[t] = v; __syncthreads();
    for (int o = 1; o < 256; o <<= 1) {
        int u = (t >= o) ? s[t - o] : 0;
        __syncthreads();
        s[t] += u;
        __syncthreads();
    }
    if (i < n) rowp[i] = s[t] - v;              // exclusive, block-local
    if (t == 255) bsums[blockIdx.x] = s[255];
}

__global__ void k_scan_sums(int* __restrict__ bsums, int nb) {
    __shared__ int s[512];
    int t = threadIdx.x;
    int v = (t < nb) ? bsums[t] : 0;
    s[t] = v; __syncthreads();
    for (int o = 1; o < 512; o <<= 1) {
        int u = (t >= o) ? s[t - o] : 0;
        __syncthreads();
        s[t] += u;
        __syncthreads();
    }
    if (t < nb) bsums[t] = s[t] - v;            // exclusive block offsets
}

__global__ void k_add_off(int* __restrict__ rowp, const int* __restrict__ bsums, int n, int E) {
    int i = blockIdx.x * 256 + threadIdx.x;
    if (i < n) rowp[i] += bsums[blockIdx.x];
    if (i == 0) rowp[n] = E;
}

__global__ void k_scatter(const int* __restrict__ ei, int* __restrict__ fill,
                          int* __restrict__ col, int E) {
    int e = blockIdx.x * 256 + threadIdx.x;
    if (e >= E) return;
    int s = ei[e];                              // src
    int d = ei[E + e];                          // dst
    int pos = atomicAdd(&fill[d], 1);
    col[pos] = s;
}

__global__ void k_scan_g(const int* __restrict__ bcnt, int* __restrict__ gp) {
    __shared__ int s[256];
    int t = threadIdx.x;
    int v = bcnt[t];
    s[t] = v; __syncthreads();
    for (int o = 1; o < 256; o <<= 1) {
        int u = (t >= o) ? s[t - o] : 0;
        __syncthreads();
        s[t] += u;
        __syncthreads();
    }
    gp[t + 1] = s[t];
    if (t == 0) gp[0] = 0;
}

// ---------------- aggregation: z = h + sum_{j->i} h_j  (CSR gather) ----------------
__global__ void k_aggregate(const bf16* __restrict__ h, const int* __restrict__ rowp,
                            const int* __restrict__ col, bf16* __restrict__ z, int n) {
    int wid = threadIdx.x >> 6, lane = threadIdx.x & 63;
    int node = blockIdx.x * 4 + wid;            // one wave per node
    if (node >= n) return;
    const bf162* hp = (const bf162*)h;
    bf162 self = hp[node * 64 + lane];
    float ax = __bfloat162float(self.x), ay = __bfloat162float(self.y);
    int e = rowp[node], end = rowp[node + 1];
    for (; e + 3 < end; e += 4) {
        int j0 = col[e], j1 = col[e + 1], j2 = col[e + 2], j3 = col[e + 3];
        bf162 v0 = hp[j0 * 64 + lane];
        bf162 v1 = hp[j1 * 64 + lane];
        bf162 v2 = hp[j2 * 64 + lane];
        bf162 v3 = hp[j3 * 64 + lane];
        ax += __bfloat162float(v0.x) + __bfloat162float(v1.x)
            + __bfloat162float(v2.x) + __bfloat162float(v3.x);
        ay += __bfloat162float(v0.y) + __bfloat162float(v1.y)
            + __bfloat162float(v2.y) + __bfloat162float(v3.y);
    }
    for (; e < end; ++e) {
        int j = col[e];
        bf162 v = hp[j * 64 + lane];
        ax += __bfloat162float(v.x); ay += __bfloat162float(v.y);
    }
    bf162 r; r.x = __float2bfloat16(ax); r.y = __float2bfloat16(ay);
    ((bf162*)z)[node * 64 + lane] = r;
}

// ---------------- GEMM: [M,128]x[128,128] bf16 MFMA, fused epilogue, in-place safe --
// MODE 0: out = relu(acc*s[c] + t[c])   (Linear+BN+ReLU)
// MODE 1: out = relu(acc + t[c])        (Linear+bias+ReLU)
template<int MODE>
__global__ __launch_bounds__(256) void k_gemm(const bf16* __restrict__ A,
                                              const bf16* __restrict__ Bp,
                                              const float* __restrict__ sv,
                                              const float* __restrict__ tv,
                                              bf16* __restrict__ Out, int M) {
    __shared__ __align__(16) bf16 As[64 * 136];   // +8 pad: 2-way LDS conflict (free)
    __shared__ __align__(16) bf16 Bs[16384];      // frag-packed, conflict-free
    const int tid = threadIdx.x;
    const int m0 = blockIdx.x * 64;
    {
        int c = (tid & 15) * 8;
        int r0 = tid >> 4;
        #pragma unroll
        for (int rr = 0; rr < 4; ++rr) {
            int r = r0 + rr * 16;
            int gr = m0 + r;
            uint4 val = make_uint4(0, 0, 0, 0);
            if (gr < M) val = *(const uint4*)(A + (size_t)gr * 128 + c);
            *(uint4*)(As + r * 136 + c) = val;
        }
        const uint4* Bg = (const uint4*)Bp;
        uint4* Bl = (uint4*)Bs;
        #pragma unroll
        for (int i = 0; i < 8; ++i) Bl[tid + i * 256] = Bg[tid + i * 256];
    }
    __syncthreads();
    const int lane = tid & 63;
    const int wid = tid >> 6;
    const int wm = wid & 1, wn = wid >> 1;
    const int l15 = lane & 15, quad = lane >> 4;
    f32x4 acc[2][4];
    #pragma unroll
    for (int i = 0; i < 2; ++i)
        #pragma unroll
        for (int j = 0; j < 4; ++j) acc[i][j] = (f32x4){0.f, 0.f, 0.f, 0.f};
    #pragma unroll
    for (int kk = 0; kk < 4; ++kk) {
        bf16x8 a[2], b[4];
        #pragma unroll
        for (int tm = 0; tm < 2; ++tm)
            a[tm] = *(const bf16x8*)(As + (wm * 32 + tm * 16 + l15) * 136 + kk * 32 + quad * 8);
        #pragma unroll
        for (int tn = 0; tn < 4; ++tn)
            b[tn] = *(const bf16x8*)(Bs + ((kk * 4 + quad) * 128 + wn * 64 + tn * 16 + l15) * 8);
        #pragma unroll
        for (int tm = 0; tm < 2; ++tm)
            #pragma unroll
            for (int tn = 0; tn < 4; ++tn)
                acc[tm][tn] = __builtin_amdgcn_mfma_f32_16x16x32_bf16(a[tm], b[tn], acc[tm][tn], 0, 0, 0);
    }
    #pragma unroll
    for (int tn = 0; tn < 4; ++tn) {
        int gc = wn * 64 + tn * 16 + l15;
        float scale = 1.0f;
        if constexpr (MODE == 0) scale = sv[gc];
        float shift = tv[gc];
        #pragma unroll
        for (int tm = 0; tm < 2; ++tm) {
            #pragma unroll
            for (int r = 0; r < 4; ++r) {
                int gr = m0 + wm * 32 + tm * 16 + quad * 4 + r;   // C/D: col=lane&15, row=quad*4+reg
                if (gr < M) {
                    float v = acc[tm][tn][r];
                    if constexpr (MODE == 0) v = v * scale + shift; else v = v + shift;
                    v = fmaxf(v, 0.f);
                    Out[(size_t)gr * 128 + gc] = __float2bfloat16(v);
                }
            }
        }
    }
}

// ---------------- pooling (sorted batch -> contiguous ranges) ----------------
__global__ void k_pool(const bf16* __restrict__ h, const int* __restrict__ gp,
                       float* __restrict__ hg) {
    int g = blockIdx.x, t = threadIdx.x;       // 128 threads
    int s = gp[g], e = gp[g + 1];
    float acc = 0.f;
    for (int i = s; i < e; ++i) acc += __bfloat162float(h[(size_t)i * 128 + t]);
    int c = e - s; if (c < 1) c = 1;
    hg[g * 128 + t] = acc / (float)c;
}

// ---------------- projection + LayerNorm (fp32) ----------------
__global__ void k_proj_ln(const float* __restrict__ hg, const float* __restrict__ Wp,
                          const float* __restrict__ bp, const float* __restrict__ lng,
                          const float* __restrict__ lnb, float* __restrict__ out) {
    __shared__ float row[128];
    __shared__ float red[128];
    int g = blockIdx.x, t = threadIdx.x;
    row[t] = hg[g * 128 + t];
    __syncthreads();
    float p = bp[t];
    #pragma unroll 8
    for (int k = 0; k < 128; ++k) p += row[k] * Wp[k * 128 + t];
    red[t] = p; __syncthreads();
    for (int o = 64; o > 0; o >>= 1) { if (t < o) red[t] += red[t + o]; __syncthreads(); }
    float mu = red[0] * (1.0f / 128.0f);
    __syncthreads();
    float d = p - mu;
    red[t] = d * d; __syncthreads();
    for (int o = 64; o > 0; o >>= 1) { if (t < o) red[t] += red[t + o]; __syncthreads(); }
    float var = red[0] * (1.0f / 128.0f);
    out[g * 128 + t] = d * rsqrtf(var + 1e-5f) * lng[t] + lnb[t];
}

extern "C" void kernel_launch(void* const* d_in, const int* in_sizes, int n_in,
                              void* d_out, int out_size, void* d_ws, size_t ws_size,
                              hipStream_t stream) {
    const float* x   = (const float*)d_in[0];
    const int*   ei  = (const int*)d_in[1];    // int32 on device: [src(E), dst(E)]
    const int*   bat = (const int*)d_in[2];    // int32 on device
    const float* W1s = (const float*)d_in[3];
    const float* b1s = (const float*)d_in[4];
    const float* bng = (const float*)d_in[5];
    const float* bnb = (const float*)d_in[6];
    const float* bnm = (const float*)d_in[7];
    const float* bnv = (const float*)d_in[8];
    const float* W2s = (const float*)d_in[9];
    const float* b2s = (const float*)d_in[10];
    const float* Wp  = (const float*)d_in[11];
    const float* bp  = (const float*)d_in[12];
    const float* lng = (const float*)d_in[13];
    const float* lnb = (const float*)d_in[14];
    const int E = in_sizes[1] / 2;
    const int N = in_sizes[2];
    const int G = out_size / 128;

    char* w = (char*)d_ws;
    size_t off = 0;
    auto alloc = [&](size_t b) { char* p = w + off; off += (b + 255) & ~(size_t)255; return p; };
    bf16* buf_a = (bf16*)alloc((size_t)N * 128 * 2);
    bf16* buf_b = (bf16*)alloc((size_t)N * 128 * 2);
    int* col   = (int*)alloc((size_t)E * 4);
    int* cnt   = (int*)alloc((size_t)N * 4);
    int* rowp  = (int*)alloc((size_t)(N + 1) * 4);
    int* fill  = (int*)alloc((size_t)N * 4);
    int* bsums = (int*)alloc(4096);
    int* bcnt  = (int*)alloc(1024);
    int* gp    = (int*)alloc(2048);
    bf16* Wp1  = (bf16*)alloc((size_t)GDEPTH * 16384 * 2);
    bf16* Wp2  = (bf16*)alloc((size_t)GDEPTH * 16384 * 2);
    float* sA  = (float*)alloc((size_t)GDEPTH * 128 * 4);
    float* tA  = (float*)alloc((size_t)GDEPTH * 128 * 4);
    float* hg  = (float*)alloc((size_t)G * 128 * 4);

    hipMemsetAsync(cnt, 0, (size_t)N * 4, stream);
    hipMemsetAsync(bcnt, 0, (size_t)G * 4, stream);

    k_prep<<<384, 256, 0, stream>>>(W1s, W2s, b1s, bng, bnb, bnm, bnv, Wp1, Wp2, sA, tA);
    k_convert_x<<<(N * 32 + 255) / 256, 256, 0, stream>>>((const float4*)x, (bf162*)buf_a, N * 32);

    int eb = (E + 255) / 256;
    int nb = (N + 255) / 256;
    k_count<<<eb, 256, 0, stream>>>(ei, cnt, E);
    k_count_batch<<<nb, 256, 0, stream>>>(bat, bcnt, N);
    k_scan_blocks<<<nb, 256, 0, stream>>>(cnt, rowp, bsums, N);
    k_scan_sums<<<1, 512, 0, stream>>>(bsums, nb);
    k_add_off<<<nb, 256, 0, stream>>>(rowp, bsums, N, E);
    hipMemcpyAsync(fill, rowp, (size_t)N * 4, hipMemcpyDeviceToDevice, stream);
    k_scatter<<<eb, 256, 0, stream>>>(ei, fill, col, E);
    k_scan_g<<<1, 256, 0, stream>>>(bcnt, gp);

    const bf16* hcur = buf_a;
    bf16* hz = buf_b;
    for (int l = 0; l < GDEPTH; ++l) {
        k_aggregate<<<(N + 3) / 4, 256, 0, stream>>>(hcur, rowp, col, hz, N);
        k_gemm<0><<<(N + 63) / 64, 256, 0, stream>>>(hz, Wp1 + (size_t)l * 16384,
                                                     sA + l * 128, tA + l * 128, hz, N);
        k_gemm<1><<<(N + 63) / 64, 256, 0, stream>>>(hz, Wp2 + (size_t)l * 16384,
                                                     nullptr, b2s + l * 128, hz, N);
        bf16* tmp = hz; hz = (bf16*)hcur; hcur = tmp;
    }
    k_pool<<<G, 128, 0, stream>>>(hcur, gp, hg);
    k_proj_ln<<<G, 128, 0, stream>>>(hg, Wp, bp, lng, lnb, (float*)d_out);
}

// Round 3
// 706.189 us; speedup vs baseline: 1.3181x; 1.3181x over previous
//
#include <hip/hip_runtime.h>
#include <hip/hip_bf16.h>

// PatchGINEncoder on MI355X.
// R1: int inputs arrive as int32 (ei[e]=src, ei[E+e]=dst; batch int32[N]).
// R2: (a) batch is SORTED -> graph bounds via boundary scan, no atomics
//         (k_count_batch was 149us of 390-way atomic contention);
//     (b) GEMM1+GEMM2 fused into k_mlp (y stays in LDS; B-frags loaded direct
//         from global into registers -- 32KB packed weights are L1-resident);
//     (c) k_aggregate widened to bf16x8/lane, 4 edges per wave step + shfl_xor
//         butterfly (4x fewer VMEM instructions per edge).

#define GDEPTH 3

typedef __bf16 bf16x8 __attribute__((ext_vector_type(8)));
typedef float  f32x4  __attribute__((ext_vector_type(4)));
typedef __hip_bfloat16  bf16;
typedef __hip_bfloat162 bf162;

// ---------------- weight prep: pack W into B-fragment order, fold BN ----------------
// Bp[((kk*4+quad)*128 + n)*8 + j] = W[kk*32+quad*8+j][n]   (16B-contiguous frag loads)
__global__ void k_prep(const float* __restrict__ W1s, const float* __restrict__ W2s,
                       const float* __restrict__ b1s, const float* __restrict__ bng,
                       const float* __restrict__ bnb, const float* __restrict__ bnm,
                       const float* __restrict__ bnv,
                       bf16* __restrict__ Wp1, bf16* __restrict__ Wp2,
                       float* __restrict__ sArr, float* __restrict__ tArr) {
    int idx = blockIdx.x * 256 + threadIdx.x;      // [0, 6*16384)
    int l   = idx / 32768;
    int rem = idx - l * 32768;
    int w   = rem >> 14;
    int p   = rem & 16383;
    int j = p & 7, n = (p >> 3) & 127, tq = p >> 10;
    int quad = tq & 3, kk = tq >> 2;
    int k = kk * 32 + quad * 8 + j;
    const float* W = w ? W2s : W1s;
    bf16* Wp = w ? Wp2 : Wp1;
    Wp[l * 16384 + p] = __float2bfloat16(W[l * 16384 + k * 128 + n]);
    if (idx < GDEPTH * 128) {
        int ll = idx >> 7, c = idx & 127;
        float inv = rsqrtf(bnv[ll * 128 + c] + 1e-5f);
        float s = inv * bng[ll * 128 + c];
        sArr[idx] = s;
        tArr[idx] = (b1s[ll * 128 + c] - bnm[ll * 128 + c]) * s + bnb[ll * 128 + c];
    }
}

__global__ void k_convert_x(const float4* __restrict__ x, bf162* __restrict__ h, int n4) {
    int i = blockIdx.x * 256 + threadIdx.x;
    if (i >= n4) return;
    float4 v = x[i];
    bf162 a, b;
    a.x = __float2bfloat16(v.x); a.y = __float2bfloat16(v.y);
    b.x = __float2bfloat16(v.z); b.y = __float2bfloat16(v.w);
    h[2 * i] = a; h[2 * i + 1] = b;
}

// ---------------- CSR build (int32 indices) ----------------
__global__ void k_count(const int* __restrict__ ei, int* __restrict__ cnt, int E) {
    int e = blockIdx.x * 256 + threadIdx.x;
    if (e >= E) return;
    atomicAdd(&cnt[ei[E + e]], 1);             // dst row of edge_index
}

__global__ void k_scan_blocks(const int* __restrict__ cnt, int* __restrict__ rowp,
                              int* __restrict__ bsums, int n) {
    __shared__ int s[256];
    int t = threadIdx.x;
    int i = blockIdx.x * 256 + t;
    int v = (i < n) ? cnt[i] : 0;
    s[t] = v; __syncthreads();
    for (int o = 1; o < 256; o <<= 1) {
        int u = (t >= o) ? s[t - o] : 0;
        __syncthreads();
        s[t] += u;
        __syncthreads();
    }
    if (i < n) rowp[i] = s[t] - v;              // exclusive, block-local
    if (t == 255) bsums[blockIdx.x] = s[255];
}

__global__ void k_scan_sums(int* __restrict__ bsums, int nb) {
    __shared__ int s[512];
    int t = threadIdx.x;
    int v = (t < nb) ? bsums[t] : 0;
    s[t] = v; __syncthreads();
    for (int o = 1; o < 512; o <<= 1) {
        int u = (t >= o) ? s[t - o] : 0;
        __syncthreads();
        s[t] += u;
        __syncthreads();
    }
    if (t < nb) bsums[t] = s[t] - v;            // exclusive block offsets
}

__global__ void k_add_off(int* __restrict__ rowp, const int* __restrict__ bsums, int n, int E) {
    int i = blockIdx.x * 256 + threadIdx.x;
    if (i < n) rowp[i] += bsums[blockIdx.x];
    if (i == 0) rowp[n] = E;
}

__global__ void k_scatter(const int* __restrict__ ei, int* __restrict__ fill,
                          int* __restrict__ col, int E) {
    int e = blockIdx.x * 256 + threadIdx.x;
    if (e >= E) return;
    int s = ei[e];                              // src
    int d = ei[E + e];                          // dst
    int pos = atomicAdd(&fill[d], 1);
    col[pos] = s;
}

// ---------------- graph bounds from SORTED batch (no atomics) ----------------
// gp[g] = first node index belonging to graph >= g; gp[G] = n.
__global__ void k_graph_bounds(const int* __restrict__ batch, int* __restrict__ gp,
                               int n, int G) {
    int i = blockIdx.x * 256 + threadIdx.x;
    if (i >= n) return;
    int b = batch[i];
    if (i == 0) {
        for (int g = 0; g <= b; ++g) gp[g] = 0;
    } else {
        int pb = batch[i - 1];
        if (pb != b) for (int g = pb + 1; g <= b; ++g) gp[g] = i;
    }
    if (i == n - 1) {
        for (int g = b + 1; g <= G; ++g) gp[g] = n;
    }
}

// ---------------- aggregation: z = h + sum_{j->i} h_j  (CSR gather, wide) --------
// One wave per node. lane = g*16+c: group g (0..3) handles edges e0+g, e0+g+4, ...;
// each lane loads 16B (8 feats) of the neighbor row. Butterfly (xor 16,32) combines.
__global__ void k_aggregate(const bf16* __restrict__ h, const int* __restrict__ rowp,
                            const int* __restrict__ col, bf16* __restrict__ z, int n) {
    int wid = threadIdx.x >> 6, lane = threadIdx.x & 63;
    int node = blockIdx.x * 4 + wid;
    if (node >= n) return;
    int g = lane >> 4, c = lane & 15;
    const bf16x8* hp8 = (const bf16x8*)h;       // row j chunk c at hp8[j*16 + c]
    float acc[8];
    #pragma unroll
    for (int k = 0; k < 8; ++k) acc[k] = 0.f;
    int start = rowp[node], end = rowp[node + 1];
    for (int e = start + g; e < end; e += 4) {
        int j = col[e];
        bf16x8 v = hp8[(size_t)j * 16 + c];
        #pragma unroll
        for (int k = 0; k < 8; ++k) acc[k] += (float)v[k];
    }
    #pragma unroll
    for (int off = 16; off <= 32; off <<= 1) {
        #pragma unroll
        for (int k = 0; k < 8; ++k) acc[k] += __shfl_xor(acc[k], off, 64);
    }
    if (g == 0) {
        bf16x8 self = hp8[(size_t)node * 16 + c];
        bf16x8 r;
        #pragma unroll
        for (int k = 0; k < 8; ++k) {
            float v = acc[k] + (float)self[k];
            __hip_bfloat16 t = __float2bfloat16(v);
            r[k] = *(__bf16*)&t;
        }
        ((bf16x8*)z)[(size_t)node * 16 + c] = r;
    }
}

// ---------------- fused MLP: relu(BN(z@W1+b1)) @ W2 + b2, relu ------------------
// Per block: 64 rows staged in LDS; GEMM1 (B1-frags in regs, direct from global);
// y written back to LDS (C-layout -> A-layout round trip); GEMM2; store.
// In-place safe: block writes only the rows it staged.
__global__ __launch_bounds__(256) void k_mlp(const bf16* __restrict__ A,
                                             const bf16* __restrict__ Bp1,
                                             const bf16* __restrict__ Bp2,
                                             const float* __restrict__ sv,
                                             const float* __restrict__ tv,
                                             const float* __restrict__ b2,
                                             bf16* __restrict__ Out, int M) {
    __shared__ __align__(16) bf16 As[64 * 136];   // +8 pad
    const int tid = threadIdx.x;
    const int m0 = blockIdx.x * 64;
    {
        int c = (tid & 15) * 8;
        int r0 = tid >> 4;
        #pragma unroll
        for (int rr = 0; rr < 4; ++rr) {
            int r = r0 + rr * 16;
            int gr = m0 + r;
            uint4 val = make_uint4(0, 0, 0, 0);
            if (gr < M) val = *(const uint4*)(A + (size_t)gr * 128 + c);
            *(uint4*)(As + r * 136 + c) = val;
        }
    }
    const int lane = tid & 63;
    const int wid = tid >> 6;
    const int wm = wid & 1, wn = wid >> 1;
    const int l15 = lane & 15, quad = lane >> 4;

    // B1 fragments: loop-invariant, direct from global (L1-resident 32KB)
    bf16x8 b1[4][4];
    #pragma unroll
    for (int kk = 0; kk < 4; ++kk)
        #pragma unroll
        for (int tn = 0; tn < 4; ++tn)
            b1[kk][tn] = *(const bf16x8*)(Bp1 + ((kk * 4 + quad) * 128 + wn * 64 + tn * 16 + l15) * 8);

    __syncthreads();
    f32x4 acc[2][4];
    #pragma unroll
    for (int i = 0; i < 2; ++i)
        #pragma unroll
        for (int j = 0; j < 4; ++j) acc[i][j] = (f32x4){0.f, 0.f, 0.f, 0.f};
    #pragma unroll
    for (int kk = 0; kk < 4; ++kk) {
        bf16x8 a[2];
        #pragma unroll
        for (int tm = 0; tm < 2; ++tm)
            a[tm] = *(const bf16x8*)(As + (wm * 32 + tm * 16 + l15) * 136 + kk * 32 + quad * 8);
        #pragma unroll
        for (int tm = 0; tm < 2; ++tm)
            #pragma unroll
            for (int tn = 0; tn < 4; ++tn)
                acc[tm][tn] = __builtin_amdgcn_mfma_f32_16x16x32_bf16(a[tm], b1[kk][tn], acc[tm][tn], 0, 0, 0);
    }
    __syncthreads();                               // all GEMM1 A-reads done
    // epilogue1: y = relu(acc*s + t) -> LDS (C/D: col=lane&15, row=quad*4+reg)
    #pragma unroll
    for (int tn = 0; tn < 4; ++tn) {
        int gc = wn * 64 + tn * 16 + l15;
        float scale = sv[gc], shift = tv[gc];
        #pragma unroll
        for (int tm = 0; tm < 2; ++tm)
            #pragma unroll
            for (int r = 0; r < 4; ++r) {
                float v = fmaxf(acc[tm][tn][r] * scale + shift, 0.f);
                int row = wm * 32 + tm * 16 + quad * 4 + r;
                __hip_bfloat16 t = __float2bfloat16(v);
                As[row * 136 + gc] = *(bf16*)&t;
            }
    }
    // B2 fragments
    bf16x8 b2f[4][4];
    #pragma unroll
    for (int kk = 0; kk < 4; ++kk)
        #pragma unroll
        for (int tn = 0; tn < 4; ++tn)
            b2f[kk][tn] = *(const bf16x8*)(Bp2 + ((kk * 4 + quad) * 128 + wn * 64 + tn * 16 + l15) * 8);
    __syncthreads();                               // y fully in LDS
    #pragma unroll
    for (int i = 0; i < 2; ++i)
        #pragma unroll
        for (int j = 0; j < 4; ++j) acc[i][j] = (f32x4){0.f, 0.f, 0.f, 0.f};
    #pragma unroll
    for (int kk = 0; kk < 4; ++kk) {
        bf16x8 a[2];
        #pragma unroll
        for (int tm = 0; tm < 2; ++tm)
            a[tm] = *(const bf16x8*)(As + (wm * 32 + tm * 16 + l15) * 136 + kk * 32 + quad * 8);
        #pragma unroll
        for (int tm = 0; tm < 2; ++tm)
            #pragma unroll
            for (int tn = 0; tn < 4; ++tn)
                acc[tm][tn] = __builtin_amdgcn_mfma_f32_16x16x32_bf16(a[tm], b2f[kk][tn], acc[tm][tn], 0, 0, 0);
    }
    // epilogue2: h = relu(acc + b2) -> global
    #pragma unroll
    for (int tn = 0; tn < 4; ++tn) {
        int gc = wn * 64 + tn * 16 + l15;
        float shift = b2[gc];
        #pragma unroll
        for (int tm = 0; tm < 2; ++tm)
            #pragma unroll
            for (int r = 0; r < 4; ++r) {
                int gr = m0 + wm * 32 + tm * 16 + quad * 4 + r;
                if (gr < M) {
                    float v = fmaxf(acc[tm][tn][r] + shift, 0.f);
                    Out[(size_t)gr * 128 + gc] = __float2bfloat16(v);
                }
            }
    }
}

// ---------------- pooling (sorted batch -> contiguous ranges) ----------------
__global__ void k_pool(const bf16* __restrict__ h, const int* __restrict__ gp,
                       float* __restrict__ hg) {
    int g = blockIdx.x, t = threadIdx.x;       // 128 threads
    int s = gp[g], e = gp[g + 1];
    float acc = 0.f;
    for (int i = s; i < e; ++i) acc += __bfloat162float(h[(size_t)i * 128 + t]);
    int c = e - s; if (c < 1) c = 1;
    hg[g * 128 + t] = acc / (float)c;
}

// ---------------- projection + LayerNorm (fp32) ----------------
__global__ void k_proj_ln(const float* __restrict__ hg, const float* __restrict__ Wp,
                          const float* __restrict__ bp, const float* __restrict__ lng,
                          const float* __restrict__ lnb, float* __restrict__ out) {
    __shared__ float row[128];
    __shared__ float red[128];
    int g = blockIdx.x, t = threadIdx.x;
    row[t] = hg[g * 128 + t];
    __syncthreads();
    float p = bp[t];
    #pragma unroll 8
    for (int k = 0; k < 128; ++k) p += row[k] * Wp[k * 128 + t];
    red[t] = p; __syncthreads();
    for (int o = 64; o > 0; o >>= 1) { if (t < o) red[t] += red[t + o]; __syncthreads(); }
    float mu = red[0] * (1.0f / 128.0f);
    __syncthreads();
    float d = p - mu;
    red[t] = d * d; __syncthreads();
    for (int o = 64; o > 0; o >>= 1) { if (t < o) red[t] += red[t + o]; __syncthreads(); }
    float var = red[0] * (1.0f / 128.0f);
    out[g * 128 + t] = d * rsqrtf(var + 1e-5f) * lng[t] + lnb[t];
}

extern "C" void kernel_launch(void* const* d_in, const int* in_sizes, int n_in,
                              void* d_out, int out_size, void* d_ws, size_t ws_size,
                              hipStream_t stream) {
    const float* x   = (const float*)d_in[0];
    const int*   ei  = (const int*)d_in[1];    // int32: [src(E), dst(E)]
    const int*   bat = (const int*)d_in[2];    // int32, sorted
    const float* W1s = (const float*)d_in[3];
    const float* b1s = (const float*)d_in[4];
    const float* bng = (const float*)d_in[5];
    const float* bnb = (const float*)d_in[6];
    const float* bnm = (const float*)d_in[7];
    const float* bnv = (const float*)d_in[8];
    const float* W2s = (const float*)d_in[9];
    const float* b2s = (const float*)d_in[10];
    const float* Wp  = (const float*)d_in[11];
    const float* bp  = (const float*)d_in[12];
    const float* lng = (const float*)d_in[13];
    const float* lnb = (const float*)d_in[14];
    const int E = in_sizes[1] / 2;
    const int N = in_sizes[2];
    const int G = out_size / 128;

    char* w = (char*)d_ws;
    size_t off = 0;
    auto alloc = [&](size_t b) { char* p = w + off; off += (b + 255) & ~(size_t)255; return p; };
    bf16* buf_a = (bf16*)alloc((size_t)N * 128 * 2);
    bf16* buf_b = (bf16*)alloc((size_t)N * 128 * 2);
    int* col   = (int*)alloc((size_t)E * 4);
    int* cnt   = (int*)alloc((size_t)N * 4);
    int* rowp  = (int*)alloc((size_t)(N + 1) * 4);
    int* fill  = (int*)alloc((size_t)N * 4);
    int* bsums = (int*)alloc(4096);
    int* gp    = (int*)alloc(2048);
    bf16* Wp1  = (bf16*)alloc((size_t)GDEPTH * 16384 * 2);
    bf16* Wp2  = (bf16*)alloc((size_t)GDEPTH * 16384 * 2);
    float* sA  = (float*)alloc((size_t)GDEPTH * 128 * 4);
    float* tA  = (float*)alloc((size_t)GDEPTH * 128 * 4);
    float* hg  = (float*)alloc((size_t)G * 128 * 4);

    hipMemsetAsync(cnt, 0, (size_t)N * 4, stream);

    k_prep<<<384, 256, 0, stream>>>(W1s, W2s, b1s, bng, bnb, bnm, bnv, Wp1, Wp2, sA, tA);
    k_convert_x<<<(N * 32 + 255) / 256, 256, 0, stream>>>((const float4*)x, (bf162*)buf_a, N * 32);

    int eb = (E + 255) / 256;
    int nb = (N + 255) / 256;
    k_count<<<eb, 256, 0, stream>>>(ei, cnt, E);
    k_graph_bounds<<<nb, 256, 0, stream>>>(bat, gp, N, G);
    k_scan_blocks<<<nb, 256, 0, stream>>>(cnt, rowp, bsums, N);
    k_scan_sums<<<1, 512, 0, stream>>>(bsums, nb);
    k_add_off<<<nb, 256, 0, stream>>>(rowp, bsums, N, E);
    hipMemcpyAsync(fill, rowp, (size_t)N * 4, hipMemcpyDeviceToDevice, stream);
    k_scatter<<<eb, 256, 0, stream>>>(ei, fill, col, E);

    const bf16* hcur = buf_a;
    bf16* hz = buf_b;
    for (int l = 0; l < GDEPTH; ++l) {
        k_aggregate<<<(N + 3) / 4, 256, 0, stream>>>(hcur, rowp, col, hz, N);
        k_mlp<<<(N + 63) / 64, 256, 0, stream>>>(hz, Wp1 + (size_t)l * 16384,
                                                 Wp2 + (size_t)l * 16384,
                                                 sA + l * 128, tA + l * 128,
                                                 b2s + l * 128, hz, N);
        bf16* tmp = hz; hz = (bf16*)hcur; hcur = tmp;
    }
    k_pool<<<G, 128, 0, stream>>>(hcur, gp, hg);
    k_proj_ln<<<G, 128, 0, stream>>>(hg, Wp, bp, lng, lnb, (float*)d_out);
}